// Round 1
// baseline (1663.134 us; speedup 1.0000x reference)
//
#include <hip/hip_runtime.h>

#define E_ 8
#define H_ 1024
#define I_ 2816
#define GU_ 5632
#define T_ 8192

typedef __attribute__((ext_vector_type(8))) __bf16 bf16x8;
typedef __attribute__((ext_vector_type(4))) float f32x4;
typedef __attribute__((ext_vector_type(8))) unsigned short u16x8;
typedef unsigned short u16;

__device__ __forceinline__ float bf2f(u16 u) {
  union { unsigned int i; float f; } v; v.i = ((unsigned int)u) << 16; return v.f;
}
__device__ __forceinline__ u16 f2bf(float f) {
  union { float f; unsigned int i; } v; v.f = f;
  unsigned int r = v.i + 0x7fffu + ((v.i >> 16) & 1u);
  return (u16)(r >> 16);
}
__device__ __forceinline__ void gld16(const void* g, void* l) {
  __builtin_amdgcn_global_load_lds((const __attribute__((address_space(1))) void*)g,
                                   (__attribute__((address_space(3))) void*)l, 16, 0, 0);
}

// ---------------- router: logits, softmax, top-2, x->bf16 ----------------
__global__ __launch_bounds__(256) void k_router(
    const float* __restrict__ x, const float* __restrict__ gw,
    float* __restrict__ imp, int* __restrict__ counts,
    int* __restrict__ tok_e, float* __restrict__ tok_w,
    u16* __restrict__ xb)
{
  const int t = blockIdx.x * 4 + (threadIdx.x >> 6);
  const int lane = threadIdx.x & 63;
  const float* xr = x + (size_t)t * H_;
  const f32x4* xp = (const f32x4*)(xr + lane * 16);
  f32x4 v0 = xp[0], v1 = xp[1], v2 = xp[2], v3 = xp[3];
  float xv[16];
#pragma unroll
  for (int b = 0; b < 4; ++b) { xv[b] = v0[b]; xv[4+b] = v1[b]; xv[8+b] = v2[b]; xv[12+b] = v3[b]; }
  u16x8 o0, o1;
#pragma unroll
  for (int j = 0; j < 8; ++j) { o0[j] = f2bf(xv[j]); o1[j] = f2bf(xv[8 + j]); }
  *(u16x8*)(xb + (size_t)t * H_ + lane * 16) = o0;
  *(u16x8*)(xb + (size_t)t * H_ + lane * 16 + 8) = o1;

  float lg[8];
#pragma unroll
  for (int e = 0; e < 8; ++e) {
    const f32x4* gp = (const f32x4*)(gw + e * H_ + lane * 16);
    float s = 0.f;
#pragma unroll
    for (int a = 0; a < 4; ++a) {
      f32x4 g4 = gp[a];
#pragma unroll
      for (int b = 0; b < 4; ++b) s += xv[a * 4 + b] * g4[b];
    }
    lg[e] = s;
  }
#pragma unroll
  for (int e = 0; e < 8; ++e)
#pragma unroll
    for (int off = 32; off; off >>= 1) lg[e] += __shfl_xor(lg[e], off);

  float m = lg[0];
#pragma unroll
  for (int e = 1; e < 8; ++e) m = fmaxf(m, lg[e]);
  float p[8], sum = 0.f;
#pragma unroll
  for (int e = 0; e < 8; ++e) { p[e] = __expf(lg[e] - m); sum += p[e]; }
  float inv = 1.f / sum;
#pragma unroll
  for (int e = 0; e < 8; ++e) p[e] *= inv;
  int e0 = 0;
#pragma unroll
  for (int e = 1; e < 8; ++e) if (p[e] > p[e0]) e0 = e;
  int e1 = (e0 == 0) ? 1 : 0;
#pragma unroll
  for (int e = 0; e < 8; ++e) if (e != e0 && p[e] > p[e1]) e1 = e;
  float d = 1.f / (p[e0] + p[e1]);
  if (lane == 0) {
#pragma unroll
    for (int e = 0; e < 8; ++e) atomicAdd(&imp[e], p[e]);
    atomicAdd(&counts[e0], 1);
    atomicAdd(&counts[e1], 1);
    tok_e[2 * t] = e0; tok_e[2 * t + 1] = e1;
    tok_w[2 * t] = p[e0] * d; tok_w[2 * t + 1] = p[e1] * d;
  }
}

// ---------------- transpose+convert: src[z][R][C] f32 -> dst[z][C][R] bf16 ----------------
__global__ __launch_bounds__(256) void k_transpose(
    const float* __restrict__ src, u16* __restrict__ dst, int R, int C)
{
  __shared__ float tile[32][33];
  const int z = blockIdx.z;
  const int c0 = blockIdx.x * 32, r0 = blockIdx.y * 32;
  const float* s = src + (size_t)z * R * C;
  u16* d = dst + (size_t)z * R * C;
  const int tx = threadIdx.x & 31, ty = threadIdx.x >> 5;
#pragma unroll
  for (int i = 0; i < 4; ++i)
    tile[ty + i * 8][tx] = s[(size_t)(r0 + ty + i * 8) * C + c0 + tx];
  __syncthreads();
#pragma unroll
  for (int i = 0; i < 4; ++i)
    d[(size_t)(c0 + ty + i * 8) * R + r0 + tx] = f2bf(tile[tx][ty + i * 8]);
}

// ---------------- scan counts + aux loss ----------------
__global__ void k_scan_aux(const int* __restrict__ counts, int* __restrict__ offsets,
                           const float* __restrict__ imp, float* __restrict__ out)
{
  if (threadIdx.x == 0 && blockIdx.x == 0) {
    int off = 0; float aux = 0.f;
    for (int e = 0; e < 8; ++e) { offsets[e] = off; off += counts[e]; aux += imp[e] * (float)counts[e]; }
    out[(size_t)T_ * H_] = 8.f * aux / ((float)T_ * (float)(2 * T_));
  }
}

// ---------------- scatter tokens into per-expert segments ----------------
__global__ __launch_bounds__(256) void k_scatter(
    const int* __restrict__ tok_e, const float* __restrict__ tok_w,
    const int* __restrict__ offsets, int* __restrict__ cursors,
    int* __restrict__ rows, float* __restrict__ wslot, int* __restrict__ t2s)
{
  const int t = blockIdx.x * 256 + threadIdx.x;
#pragma unroll
  for (int j = 0; j < 2; ++j) {
    int e = tok_e[2 * t + j];
    int pos = atomicAdd(&cursors[e], 1);
    int slot = offsets[e] + pos;
    rows[slot] = t;
    wslot[slot] = tok_w[2 * t + j];
    t2s[2 * t + j] = slot;
  }
}

// ---------------- GEMM1: act[slot][i] = w * silu(x@Wg) * (x@Wu), bf16 ----------------
__global__ __launch_bounds__(256, 2) void k_gemm1(
    const u16* __restrict__ xb, const u16* __restrict__ wgu_t,
    const int* __restrict__ counts, const int* __restrict__ offsets,
    const int* __restrict__ rows, const float* __restrict__ wslot,
    u16* __restrict__ act)
{
  const int e = blockIdx.z;
  const int cnt = counts[e];
  const int m0 = blockIdx.x * 128;
  if (m0 >= cnt) return;
  const int seg = offsets[e];
  const int segLast = seg + cnt - 1;
  const int n0 = blockIdx.y * 64;

  __shared__ alignas(16) u16 As[128 * 64];
  __shared__ alignas(16) u16 Bg[64 * 64];
  __shared__ alignas(16) u16 Bu[64 * 64];

  const int tid = threadIdx.x;
  const int wid = tid >> 6;
  const int lane = tid & 63;
  const int laneK = (lane & 7) * 8;

  int tA[4];
#pragma unroll
  for (int i = 0; i < 4; ++i) {
    int slot = seg + m0 + wid * 32 + i * 8 + (lane >> 3);
    tA[i] = rows[slot > segLast ? segLast : slot];
  }
  int bR[2];
#pragma unroll
  for (int i = 0; i < 2; ++i) bR[i] = wid * 16 + i * 8 + (lane >> 3);

  const u16* wge = wgu_t + (size_t)e * GU_ * H_;

  f32x4 accg[4][2], accu[4][2];
#pragma unroll
  for (int a = 0; a < 4; ++a)
#pragma unroll
    for (int b = 0; b < 2; ++b) { accg[a][b] = (f32x4){0.f,0.f,0.f,0.f}; accu[a][b] = (f32x4){0.f,0.f,0.f,0.f}; }

  const int wm = (wid >> 1) * 64;
  const int wn = (wid & 1) * 32;

  for (int kt = 0; kt < 16; ++kt) {
    const int k0 = kt * 64;
#pragma unroll
    for (int i = 0; i < 4; ++i)
      gld16(xb + (size_t)tA[i] * H_ + k0 + laneK, (char*)As + wid * 4096 + i * 1024);
#pragma unroll
    for (int i = 0; i < 2; ++i) {
      gld16(wge + (size_t)(n0 + bR[i]) * H_ + k0 + laneK, (char*)Bg + wid * 2048 + i * 1024);
      gld16(wge + (size_t)(I_ + n0 + bR[i]) * H_ + k0 + laneK, (char*)Bu + wid * 2048 + i * 1024);
    }
    __syncthreads();
#pragma unroll
    for (int ks = 0; ks < 2; ++ks) {
      const int kk = ks * 32 + (lane >> 4) * 8;
      bf16x8 a[4], bg[2], bu[2];
#pragma unroll
      for (int mf = 0; mf < 4; ++mf)
        a[mf] = *(const bf16x8*)(As + (wm + mf * 16 + (lane & 15)) * 64 + kk);
#pragma unroll
      for (int nf = 0; nf < 2; ++nf) {
        bg[nf] = *(const bf16x8*)(Bg + (wn + nf * 16 + (lane & 15)) * 64 + kk);
        bu[nf] = *(const bf16x8*)(Bu + (wn + nf * 16 + (lane & 15)) * 64 + kk);
      }
#pragma unroll
      for (int mf = 0; mf < 4; ++mf)
#pragma unroll
        for (int nf = 0; nf < 2; ++nf) {
          accg[mf][nf] = __builtin_amdgcn_mfma_f32_16x16x32_bf16(a[mf], bg[nf], accg[mf][nf], 0, 0, 0);
          accu[mf][nf] = __builtin_amdgcn_mfma_f32_16x16x32_bf16(a[mf], bu[nf], accu[mf][nf], 0, 0, 0);
        }
    }
    __syncthreads();
  }

#pragma unroll
  for (int mf = 0; mf < 4; ++mf)
#pragma unroll
    for (int reg = 0; reg < 4; ++reg) {
      const int r = wm + mf * 16 + (lane >> 4) * 4 + reg;
      if (m0 + r >= cnt) continue;
      const int slot = seg + m0 + r;
      const float w = wslot[slot];
#pragma unroll
      for (int nf = 0; nf < 2; ++nf) {
        float g = accg[mf][nf][reg];
        float u = accu[mf][nf][reg];
        float sv = (g / (1.f + __expf(-g))) * u * w;
        act[(size_t)slot * I_ + n0 + wn + nf * 16 + (lane & 15)] = f2bf(sv);
      }
    }
}

// ---------------- GEMM2: y[slot][h] = act @ Wd, bf16 ----------------
__global__ __launch_bounds__(256, 2) void k_gemm2(
    const u16* __restrict__ act, const u16* __restrict__ wd_t,
    const int* __restrict__ counts, const int* __restrict__ offsets,
    u16* __restrict__ y)
{
  const int e = blockIdx.z;
  const int cnt = counts[e];
  const int m0 = blockIdx.x * 128;
  if (m0 >= cnt) return;
  const int seg = offsets[e];
  const int segLast = seg + cnt - 1;
  const int n0 = blockIdx.y * 128;

  __shared__ alignas(16) u16 As[128 * 64];
  __shared__ alignas(16) u16 Bs[128 * 64];

  const int tid = threadIdx.x, wid = tid >> 6, lane = tid & 63;
  const int laneK = (lane & 7) * 8;
  int aSlot[4], bR[4];
#pragma unroll
  for (int i = 0; i < 4; ++i) {
    int slot = seg + m0 + wid * 32 + i * 8 + (lane >> 3);
    aSlot[i] = slot > segLast ? segLast : slot;
    bR[i] = wid * 32 + i * 8 + (lane >> 3);
  }
  const u16* wde = wd_t + (size_t)e * H_ * I_;

  f32x4 acc[4][4];
#pragma unroll
  for (int a = 0; a < 4; ++a)
#pragma unroll
    for (int b = 0; b < 4; ++b) acc[a][b] = (f32x4){0.f,0.f,0.f,0.f};

  const int wm = (wid >> 1) * 64, wn = (wid & 1) * 64;

  for (int kt = 0; kt < 44; ++kt) {
    const int k0 = kt * 64;
#pragma unroll
    for (int i = 0; i < 4; ++i)
      gld16(act + (size_t)aSlot[i] * I_ + k0 + laneK, (char*)As + wid * 4096 + i * 1024);
#pragma unroll
    for (int i = 0; i < 4; ++i)
      gld16(wde + (size_t)(n0 + bR[i]) * I_ + k0 + laneK, (char*)Bs + wid * 4096 + i * 1024);
    __syncthreads();
#pragma unroll
    for (int ks = 0; ks < 2; ++ks) {
      const int kk = ks * 32 + (lane >> 4) * 8;
      bf16x8 a[4], b[4];
#pragma unroll
      for (int mf = 0; mf < 4; ++mf)
        a[mf] = *(const bf16x8*)(As + (wm + mf * 16 + (lane & 15)) * 64 + kk);
#pragma unroll
      for (int nf = 0; nf < 4; ++nf)
        b[nf] = *(const bf16x8*)(Bs + (wn + nf * 16 + (lane & 15)) * 64 + kk);
#pragma unroll
      for (int mf = 0; mf < 4; ++mf)
#pragma unroll
        for (int nf = 0; nf < 4; ++nf)
          acc[mf][nf] = __builtin_amdgcn_mfma_f32_16x16x32_bf16(a[mf], b[nf], acc[mf][nf], 0, 0, 0);
    }
    __syncthreads();
  }
#pragma unroll
  for (int mf = 0; mf < 4; ++mf)
#pragma unroll
    for (int reg = 0; reg < 4; ++reg) {
      const int r = wm + mf * 16 + (lane >> 4) * 4 + reg;
      if (m0 + r >= cnt) continue;
      const int slot = seg + m0 + r;
#pragma unroll
      for (int nf = 0; nf < 4; ++nf)
        y[(size_t)slot * H_ + n0 + wn + nf * 16 + (lane & 15)] = f2bf(acc[mf][nf][reg]);
    }
}

// ---------------- combine: out[t] = y[slot0] + y[slot1] ----------------
__global__ __launch_bounds__(256) void k_combine(
    const u16* __restrict__ y, const int* __restrict__ t2s, float* __restrict__ out)
{
  const size_t idx = ((size_t)blockIdx.x * 256 + threadIdx.x) * 8;
  const int t = (int)(idx >> 10);
  const int h = (int)(idx & 1023);
  const int s0 = t2s[2 * t], s1 = t2s[2 * t + 1];
  u16x8 a = *(const u16x8*)(y + (size_t)s0 * H_ + h);
  u16x8 b = *(const u16x8*)(y + (size_t)s1 * H_ + h);
  f32x4 o0, o1;
#pragma unroll
  for (int j = 0; j < 4; ++j) o0[j] = bf2f(a[j]) + bf2f(b[j]);
#pragma unroll
  for (int j = 0; j < 4; ++j) o1[j] = bf2f(a[4 + j]) + bf2f(b[4 + j]);
  *(f32x4*)(out + idx) = o0;
  *(f32x4*)(out + idx + 4) = o1;
}

extern "C" void kernel_launch(void* const* d_in, const int* in_sizes, int n_in,
                              void* d_out, int out_size, void* d_ws, size_t ws_size,
                              hipStream_t stream)
{
  const float* x   = (const float*)d_in[0];
  const float* gw  = (const float*)d_in[1];
  const float* wgu = (const float*)d_in[2];
  const float* wd  = (const float*)d_in[3];
  float* out = (float*)d_out;
  char* ws = (char*)d_ws;

  const size_t off_wgu_t = 0;
  const size_t off_wd_t  = off_wgu_t + (size_t)E_ * GU_ * H_ * 2;   // 92,274,688
  const size_t off_xb    = off_wd_t  + (size_t)E_ * H_ * I_ * 2;    // +46,137,344
  const size_t off_act   = off_xb    + (size_t)T_ * H_ * 2;         // +16,777,216
  const size_t off_ctrl  = off_act   + (size_t)2 * T_ * I_ * 2;     // +92,274,688
  const size_t need = off_ctrl + 128 + 5 * 65536;
  if (ws_size < need) return;  // workspace too small — will show as absmax failure

  u16* wgu_t = (u16*)(ws + off_wgu_t);
  u16* wd_t  = (u16*)(ws + off_wd_t);
  u16* xb    = (u16*)(ws + off_xb);
  u16* act   = (u16*)(ws + off_act);
  u16* y     = (u16*)(ws + off_wgu_t);  // alias: wgu_t dead after gemm1
  char* ctrl = ws + off_ctrl;
  int*   counts  = (int*)(ctrl + 0);
  int*   cursors = (int*)(ctrl + 32);
  float* imp     = (float*)(ctrl + 64);
  int*   offsets = (int*)(ctrl + 96);
  int*   tok_e   = (int*)(ctrl + 128);
  float* tok_w   = (float*)(ctrl + 128 + 1 * 65536);
  int*   rows    = (int*)(ctrl + 128 + 2 * 65536);
  float* wslot   = (float*)(ctrl + 128 + 3 * 65536);
  int*   t2s     = (int*)(ctrl + 128 + 4 * 65536);

  hipMemsetAsync(ctrl, 0, 96, stream);
  hipLaunchKernelGGL(k_transpose, dim3(GU_ / 32, H_ / 32, E_), dim3(256), 0, stream, wgu, wgu_t, H_, GU_);
  hipLaunchKernelGGL(k_transpose, dim3(H_ / 32, I_ / 32, E_), dim3(256), 0, stream, wd, wd_t, I_, H_);
  hipLaunchKernelGGL(k_router, dim3(T_ / 4), dim3(256), 0, stream, x, gw, imp, counts, tok_e, tok_w, xb);
  hipLaunchKernelGGL(k_scan_aux, dim3(1), dim3(64), 0, stream, counts, offsets, imp, out);
  hipLaunchKernelGGL(k_scatter, dim3(T_ / 256), dim3(256), 0, stream, tok_e, tok_w, offsets, cursors, rows, wslot, t2s);
  hipLaunchKernelGGL(k_gemm1, dim3(64, I_ / 64, E_), dim3(256), 0, stream, xb, wgu_t, counts, offsets, rows, wslot, act);
  hipLaunchKernelGGL(k_gemm2, dim3(64, H_ / 128, E_), dim3(256), 0, stream, act, wd_t, counts, offsets, y);
  hipLaunchKernelGGL(k_combine, dim3((T_ * H_) / (256 * 8)), dim3(256), 0, stream, y, t2s, out);
}

// Round 2
// 772.813 us; speedup vs baseline: 2.1521x; 2.1521x over previous
//
#include <hip/hip_runtime.h>

#define E_ 8
#define H_ 1024
#define I_ 2816
#define GU_ 5632
#define T_ 8192
#define NBR_ 2048  // router blocks = T_/4

typedef __attribute__((ext_vector_type(8))) __bf16 bf16x8;
typedef __attribute__((ext_vector_type(4))) float f32x4;
typedef __attribute__((ext_vector_type(8))) unsigned short u16x8;
typedef unsigned short u16;

__device__ __forceinline__ float bf2f(u16 u) {
  union { unsigned int i; float f; } v; v.i = ((unsigned int)u) << 16; return v.f;
}
__device__ __forceinline__ u16 f2bf(float f) {
  union { float f; unsigned int i; } v; v.f = f;
  unsigned int r = v.i + 0x7fffu + ((v.i >> 16) & 1u);
  return (u16)(r >> 16);
}
__device__ __forceinline__ void gld16(const void* g, void* l) {
  __builtin_amdgcn_global_load_lds((const __attribute__((address_space(1))) void*)g,
                                   (__attribute__((address_space(3))) void*)l, 16, 0, 0);
}

// ---------------- router: logits, softmax, top-2, x->bf16, per-block partials ----------------
__global__ __launch_bounds__(256) void k_router(
    const float* __restrict__ x, const float* __restrict__ gw,
    float* __restrict__ part_imp, int* __restrict__ part_cnt,
    int* __restrict__ tok_e, float* __restrict__ tok_w,
    u16* __restrict__ xb)
{
  __shared__ float s_imp[8];
  __shared__ int s_cnt[8];
  if (threadIdx.x < 8) { s_imp[threadIdx.x] = 0.f; s_cnt[threadIdx.x] = 0; }
  __syncthreads();

  const int t = blockIdx.x * 4 + (threadIdx.x >> 6);
  const int lane = threadIdx.x & 63;
  const float* xr = x + (size_t)t * H_;
  const f32x4* xp = (const f32x4*)(xr + lane * 16);
  f32x4 v0 = xp[0], v1 = xp[1], v2 = xp[2], v3 = xp[3];
  float xv[16];
#pragma unroll
  for (int b = 0; b < 4; ++b) { xv[b] = v0[b]; xv[4+b] = v1[b]; xv[8+b] = v2[b]; xv[12+b] = v3[b]; }
  u16x8 o0, o1;
#pragma unroll
  for (int j = 0; j < 8; ++j) { o0[j] = f2bf(xv[j]); o1[j] = f2bf(xv[8 + j]); }
  *(u16x8*)(xb + (size_t)t * H_ + lane * 16) = o0;
  *(u16x8*)(xb + (size_t)t * H_ + lane * 16 + 8) = o1;

  float lg[8];
#pragma unroll
  for (int e = 0; e < 8; ++e) {
    const f32x4* gp = (const f32x4*)(gw + e * H_ + lane * 16);
    float s = 0.f;
#pragma unroll
    for (int a = 0; a < 4; ++a) {
      f32x4 g4 = gp[a];
#pragma unroll
      for (int b = 0; b < 4; ++b) s += xv[a * 4 + b] * g4[b];
    }
    lg[e] = s;
  }
#pragma unroll
  for (int e = 0; e < 8; ++e)
#pragma unroll
    for (int off = 32; off; off >>= 1) lg[e] += __shfl_xor(lg[e], off);

  float m = lg[0];
#pragma unroll
  for (int e = 1; e < 8; ++e) m = fmaxf(m, lg[e]);
  float p[8], sum = 0.f;
#pragma unroll
  for (int e = 0; e < 8; ++e) { p[e] = __expf(lg[e] - m); sum += p[e]; }
  float inv = 1.f / sum;
#pragma unroll
  for (int e = 0; e < 8; ++e) p[e] *= inv;
  int e0 = 0;
#pragma unroll
  for (int e = 1; e < 8; ++e) if (p[e] > p[e0]) e0 = e;
  int e1 = (e0 == 0) ? 1 : 0;
#pragma unroll
  for (int e = 0; e < 8; ++e) if (e != e0 && p[e] > p[e1]) e1 = e;
  float d = 1.f / (p[e0] + p[e1]);
  if (lane == 0) {
#pragma unroll
    for (int e = 0; e < 8; ++e) atomicAdd(&s_imp[e], p[e]);   // LDS atomics only
    atomicAdd(&s_cnt[e0], 1);
    atomicAdd(&s_cnt[e1], 1);
    tok_e[2 * t] = e0; tok_e[2 * t + 1] = e1;
    tok_w[2 * t] = p[e0] * d; tok_w[2 * t + 1] = p[e1] * d;
  }
  __syncthreads();
  if (threadIdx.x < 8) {
    part_imp[blockIdx.x * 8 + threadIdx.x] = s_imp[threadIdx.x];
    part_cnt[blockIdx.x * 8 + threadIdx.x] = s_cnt[threadIdx.x];
  }
}

// ---------------- reduce partials + offsets + aux loss (one block, 8 waves) ----------------
__global__ __launch_bounds__(512) void k_reduce_scan(
    const float* __restrict__ part_imp, const int* __restrict__ part_cnt,
    int* __restrict__ counts, int* __restrict__ offsets, float* __restrict__ out)
{
  const int w = threadIdx.x >> 6, lane = threadIdx.x & 63;
  float si = 0.f; int sc = 0;
  for (int b = lane; b < NBR_; b += 64) { si += part_imp[b * 8 + w]; sc += part_cnt[b * 8 + w]; }
#pragma unroll
  for (int off = 32; off; off >>= 1) { si += __shfl_xor(si, off); sc += __shfl_xor(sc, off); }
  __shared__ float fimp[8];
  __shared__ int fcnt[8];
  if (lane == 0) { fimp[w] = si; fcnt[w] = sc; }
  __syncthreads();
  if (threadIdx.x == 0) {
    int off = 0; float aux = 0.f;
#pragma unroll
    for (int e = 0; e < 8; ++e) {
      counts[e] = fcnt[e]; offsets[e] = off; off += fcnt[e];
      aux += fimp[e] * (float)fcnt[e];
    }
    out[(size_t)T_ * H_] = 8.f * aux / ((float)T_ * (float)(2 * T_));
  }
}

// ---------------- scatter tokens into per-expert segments (block-aggregated) ----------------
__global__ __launch_bounds__(256) void k_scatter(
    const int* __restrict__ tok_e, const float* __restrict__ tok_w,
    const int* __restrict__ offsets, int* __restrict__ cursors,
    int* __restrict__ rows, float* __restrict__ wslot, int* __restrict__ t2s)
{
  __shared__ int lcnt[8], lbase[8];
  if (threadIdx.x < 8) lcnt[threadIdx.x] = 0;
  __syncthreads();
  const int t = blockIdx.x * 256 + threadIdx.x;
  const int e0 = tok_e[2 * t], e1 = tok_e[2 * t + 1];
  const int p0 = atomicAdd(&lcnt[e0], 1);
  const int p1 = atomicAdd(&lcnt[e1], 1);
  __syncthreads();
  if (threadIdx.x < 8) lbase[threadIdx.x] = atomicAdd(&cursors[threadIdx.x], lcnt[threadIdx.x]);
  __syncthreads();
  const int s0 = offsets[e0] + lbase[e0] + p0;
  const int s1 = offsets[e1] + lbase[e1] + p1;
  rows[s0] = t; wslot[s0] = tok_w[2 * t];     t2s[2 * t] = s0;
  rows[s1] = t; wslot[s1] = tok_w[2 * t + 1]; t2s[2 * t + 1] = s1;
}

// ---------------- transpose+convert: src[z][R][C] f32 -> dst[z][C][R] bf16 ----------------
__global__ __launch_bounds__(256) void k_transpose(
    const float* __restrict__ src, u16* __restrict__ dst, int R, int C)
{
  __shared__ float tile[32][33];
  const int z = blockIdx.z;
  const int c0 = blockIdx.x * 32, r0 = blockIdx.y * 32;
  const float* s = src + (size_t)z * R * C;
  u16* d = dst + (size_t)z * R * C;
  const int tx = threadIdx.x & 31, ty = threadIdx.x >> 5;
#pragma unroll
  for (int i = 0; i < 4; ++i)
    tile[ty + i * 8][tx] = s[(size_t)(r0 + ty + i * 8) * C + c0 + tx];
  __syncthreads();
#pragma unroll
  for (int i = 0; i < 4; ++i)
    d[(size_t)(c0 + ty + i * 8) * R + r0 + tx] = f2bf(tile[tx][ty + i * 8]);
}

// ---------------- GEMM1: act[slot][i] = w * silu(x@Wg) * (x@Wu), bf16 ----------------
__global__ __launch_bounds__(256, 2) void k_gemm1(
    const u16* __restrict__ xb, const u16* __restrict__ wgu_t,
    const int* __restrict__ counts, const int* __restrict__ offsets,
    const int* __restrict__ rows, const float* __restrict__ wslot,
    u16* __restrict__ act)
{
  const int e = blockIdx.z;
  const int cnt = counts[e];
  const int m0 = blockIdx.x * 128;
  if (m0 >= cnt) return;
  const int seg = offsets[e];
  const int segLast = seg + cnt - 1;
  const int n0 = blockIdx.y * 64;

  __shared__ alignas(16) u16 As[128 * 64];
  __shared__ alignas(16) u16 Bg[64 * 64];
  __shared__ alignas(16) u16 Bu[64 * 64];

  const int tid = threadIdx.x;
  const int wid = tid >> 6;
  const int lane = tid & 63;
  const int laneK = (lane & 7) * 8;

  int tA[4];
#pragma unroll
  for (int i = 0; i < 4; ++i) {
    int slot = seg + m0 + wid * 32 + i * 8 + (lane >> 3);
    tA[i] = rows[slot > segLast ? segLast : slot];
  }
  int bR[2];
#pragma unroll
  for (int i = 0; i < 2; ++i) bR[i] = wid * 16 + i * 8 + (lane >> 3);

  const u16* wge = wgu_t + (size_t)e * GU_ * H_;

  f32x4 accg[4][2], accu[4][2];
#pragma unroll
  for (int a = 0; a < 4; ++a)
#pragma unroll
    for (int b = 0; b < 2; ++b) { accg[a][b] = (f32x4){0.f,0.f,0.f,0.f}; accu[a][b] = (f32x4){0.f,0.f,0.f,0.f}; }

  const int wm = (wid >> 1) * 64;
  const int wn = (wid & 1) * 32;

  for (int kt = 0; kt < 16; ++kt) {
    const int k0 = kt * 64;
#pragma unroll
    for (int i = 0; i < 4; ++i)
      gld16(xb + (size_t)tA[i] * H_ + k0 + laneK, (char*)As + wid * 4096 + i * 1024);
#pragma unroll
    for (int i = 0; i < 2; ++i) {
      gld16(wge + (size_t)(n0 + bR[i]) * H_ + k0 + laneK, (char*)Bg + wid * 2048 + i * 1024);
      gld16(wge + (size_t)(I_ + n0 + bR[i]) * H_ + k0 + laneK, (char*)Bu + wid * 2048 + i * 1024);
    }
    __syncthreads();
#pragma unroll
    for (int ks = 0; ks < 2; ++ks) {
      const int kk = ks * 32 + (lane >> 4) * 8;
      bf16x8 a[4], bg[2], bu[2];
#pragma unroll
      for (int mf = 0; mf < 4; ++mf)
        a[mf] = *(const bf16x8*)(As + (wm + mf * 16 + (lane & 15)) * 64 + kk);
#pragma unroll
      for (int nf = 0; nf < 2; ++nf) {
        bg[nf] = *(const bf16x8*)(Bg + (wn + nf * 16 + (lane & 15)) * 64 + kk);
        bu[nf] = *(const bf16x8*)(Bu + (wn + nf * 16 + (lane & 15)) * 64 + kk);
      }
#pragma unroll
      for (int mf = 0; mf < 4; ++mf)
#pragma unroll
        for (int nf = 0; nf < 2; ++nf) {
          accg[mf][nf] = __builtin_amdgcn_mfma_f32_16x16x32_bf16(a[mf], bg[nf], accg[mf][nf], 0, 0, 0);
          accu[mf][nf] = __builtin_amdgcn_mfma_f32_16x16x32_bf16(a[mf], bu[nf], accu[mf][nf], 0, 0, 0);
        }
    }
    __syncthreads();
  }

#pragma unroll
  for (int mf = 0; mf < 4; ++mf)
#pragma unroll
    for (int reg = 0; reg < 4; ++reg) {
      const int r = wm + mf * 16 + (lane >> 4) * 4 + reg;
      if (m0 + r >= cnt) continue;
      const int slot = seg + m0 + r;
      const float w = wslot[slot];
#pragma unroll
      for (int nf = 0; nf < 2; ++nf) {
        float g = accg[mf][nf][reg];
        float u = accu[mf][nf][reg];
        float sv = (g / (1.f + __expf(-g))) * u * w;
        act[(size_t)slot * I_ + n0 + wn + nf * 16 + (lane & 15)] = f2bf(sv);
      }
    }
}

// ---------------- GEMM2: y[slot][h] = act @ Wd, bf16 ----------------
__global__ __launch_bounds__(256, 2) void k_gemm2(
    const u16* __restrict__ act, const u16* __restrict__ wd_t,
    const int* __restrict__ counts, const int* __restrict__ offsets,
    u16* __restrict__ y)
{
  const int e = blockIdx.z;
  const int cnt = counts[e];
  const int m0 = blockIdx.x * 128;
  if (m0 >= cnt) return;
  const int seg = offsets[e];
  const int segLast = seg + cnt - 1;
  const int n0 = blockIdx.y * 128;

  __shared__ alignas(16) u16 As[128 * 64];
  __shared__ alignas(16) u16 Bs[128 * 64];

  const int tid = threadIdx.x, wid = tid >> 6, lane = tid & 63;
  const int laneK = (lane & 7) * 8;
  int aSlot[4], bR[4];
#pragma unroll
  for (int i = 0; i < 4; ++i) {
    int slot = seg + m0 + wid * 32 + i * 8 + (lane >> 3);
    aSlot[i] = slot > segLast ? segLast : slot;
    bR[i] = wid * 32 + i * 8 + (lane >> 3);
  }
  const u16* wde = wd_t + (size_t)e * H_ * I_;

  f32x4 acc[4][4];
#pragma unroll
  for (int a = 0; a < 4; ++a)
#pragma unroll
    for (int b = 0; b < 4; ++b) acc[a][b] = (f32x4){0.f,0.f,0.f,0.f};

  const int wm = (wid >> 1) * 64, wn = (wid & 1) * 64;

  for (int kt = 0; kt < 44; ++kt) {
    const int k0 = kt * 64;
#pragma unroll
    for (int i = 0; i < 4; ++i)
      gld16(act + (size_t)aSlot[i] * I_ + k0 + laneK, (char*)As + wid * 4096 + i * 1024);
#pragma unroll
    for (int i = 0; i < 4; ++i)
      gld16(wde + (size_t)(n0 + bR[i]) * I_ + k0 + laneK, (char*)Bs + wid * 4096 + i * 1024);
    __syncthreads();
#pragma unroll
    for (int ks = 0; ks < 2; ++ks) {
      const int kk = ks * 32 + (lane >> 4) * 8;
      bf16x8 a[4], b[4];
#pragma unroll
      for (int mf = 0; mf < 4; ++mf)
        a[mf] = *(const bf16x8*)(As + (wm + mf * 16 + (lane & 15)) * 64 + kk);
#pragma unroll
      for (int nf = 0; nf < 4; ++nf)
        b[nf] = *(const bf16x8*)(Bs + (wn + nf * 16 + (lane & 15)) * 64 + kk);
#pragma unroll
      for (int mf = 0; mf < 4; ++mf)
#pragma unroll
        for (int nf = 0; nf < 4; ++nf)
          acc[mf][nf] = __builtin_amdgcn_mfma_f32_16x16x32_bf16(a[mf], b[nf], acc[mf][nf], 0, 0, 0);
    }
    __syncthreads();
  }
#pragma unroll
  for (int mf = 0; mf < 4; ++mf)
#pragma unroll
    for (int reg = 0; reg < 4; ++reg) {
      const int r = wm + mf * 16 + (lane >> 4) * 4 + reg;
      if (m0 + r >= cnt) continue;
      const int slot = seg + m0 + r;
#pragma unroll
      for (int nf = 0; nf < 4; ++nf)
        y[(size_t)slot * H_ + n0 + wn + nf * 16 + (lane & 15)] = f2bf(acc[mf][nf][reg]);
    }
}

// ---------------- combine: out[t] = y[slot0] + y[slot1] ----------------
__global__ __launch_bounds__(256) void k_combine(
    const u16* __restrict__ y, const int* __restrict__ t2s, float* __restrict__ out)
{
  const size_t idx = ((size_t)blockIdx.x * 256 + threadIdx.x) * 8;
  const int t = (int)(idx >> 10);
  const int h = (int)(idx & 1023);
  const int s0 = t2s[2 * t], s1 = t2s[2 * t + 1];
  u16x8 a = *(const u16x8*)(y + (size_t)s0 * H_ + h);
  u16x8 b = *(const u16x8*)(y + (size_t)s1 * H_ + h);
  f32x4 o0, o1;
#pragma unroll
  for (int j = 0; j < 4; ++j) o0[j] = bf2f(a[j]) + bf2f(b[j]);
#pragma unroll
  for (int j = 0; j < 4; ++j) o1[j] = bf2f(a[4 + j]) + bf2f(b[4 + j]);
  *(f32x4*)(out + idx) = o0;
  *(f32x4*)(out + idx + 4) = o1;
}

extern "C" void kernel_launch(void* const* d_in, const int* in_sizes, int n_in,
                              void* d_out, int out_size, void* d_ws, size_t ws_size,
                              hipStream_t stream)
{
  const float* x   = (const float*)d_in[0];
  const float* gw  = (const float*)d_in[1];
  const float* wgu = (const float*)d_in[2];
  const float* wd  = (const float*)d_in[3];
  float* out = (float*)d_out;
  char* ws = (char*)d_ws;

  const size_t off_wgu_t = 0;
  const size_t off_wd_t  = off_wgu_t + (size_t)E_ * GU_ * H_ * 2;   // 92,274,688
  const size_t off_xb    = off_wd_t  + (size_t)E_ * H_ * I_ * 2;    // +46,137,344
  const size_t off_act   = off_xb    + (size_t)T_ * H_ * 2;         // +16,777,216
  const size_t off_ctrl  = off_act   + (size_t)2 * T_ * I_ * 2;     // +92,274,688
  const size_t need = off_ctrl + 128 + 5 * 65536;
  if (ws_size < need) return;

  u16* wgu_t = (u16*)(ws + off_wgu_t);
  u16* wd_t  = (u16*)(ws + off_wd_t);
  u16* xb    = (u16*)(ws + off_xb);
  u16* act   = (u16*)(ws + off_act);
  u16* y     = (u16*)(ws + off_wgu_t);   // alias: wgu_t dead after gemm1
  // partial arrays alias onto act region (dead until gemm1; consumed by reduce_scan)
  float* part_imp = (float*)(ws + off_act);
  int*   part_cnt = (int*)(ws + off_act + (size_t)NBR_ * 8 * 4);
  char* ctrl = ws + off_ctrl;
  int*   counts  = (int*)(ctrl + 0);
  int*   cursors = (int*)(ctrl + 32);
  int*   offsets = (int*)(ctrl + 64);
  int*   tok_e   = (int*)(ctrl + 128);
  float* tok_w   = (float*)(ctrl + 128 + 1 * 65536);
  int*   rows    = (int*)(ctrl + 128 + 2 * 65536);
  float* wslot   = (float*)(ctrl + 128 + 3 * 65536);
  int*   t2s     = (int*)(ctrl + 128 + 4 * 65536);

  hipMemsetAsync(ctrl, 0, 96, stream);
  hipLaunchKernelGGL(k_transpose, dim3(GU_ / 32, H_ / 32, E_), dim3(256), 0, stream, wgu, wgu_t, H_, GU_);
  hipLaunchKernelGGL(k_transpose, dim3(H_ / 32, I_ / 32, E_), dim3(256), 0, stream, wd, wd_t, I_, H_);
  hipLaunchKernelGGL(k_router, dim3(NBR_), dim3(256), 0, stream, x, gw, part_imp, part_cnt, tok_e, tok_w, xb);
  hipLaunchKernelGGL(k_reduce_scan, dim3(1), dim3(512), 0, stream, part_imp, part_cnt, counts, offsets, out);
  hipLaunchKernelGGL(k_scatter, dim3(T_ / 256), dim3(256), 0, stream, tok_e, tok_w, offsets, cursors, rows, wslot, t2s);
  hipLaunchKernelGGL(k_gemm1, dim3(64, I_ / 64, E_), dim3(256), 0, stream, xb, wgu_t, counts, offsets, rows, wslot, act);
  hipLaunchKernelGGL(k_gemm2, dim3(64, H_ / 128, E_), dim3(256), 0, stream, act, wd_t, counts, offsets, y);
  hipLaunchKernelGGL(k_combine, dim3((T_ * H_) / (256 * 8)), dim3(256), 0, stream, y, t2s, out);
}

// Round 3
// 655.661 us; speedup vs baseline: 2.5366x; 1.1787x over previous
//
#include <hip/hip_runtime.h>

#define E_ 8
#define H_ 1024
#define I_ 2816
#define GU_ 5632
#define T_ 8192
#define NBR_ 2048  // router blocks = T_/4

typedef __attribute__((ext_vector_type(8))) __bf16 bf16x8;
typedef __attribute__((ext_vector_type(4))) float f32x4;
typedef __attribute__((ext_vector_type(8))) unsigned short u16x8;
typedef unsigned short u16;

__device__ __forceinline__ float bf2f(u16 u) {
  union { unsigned int i; float f; } v; v.i = ((unsigned int)u) << 16; return v.f;
}
__device__ __forceinline__ u16 f2bf(float f) {
  union { float f; unsigned int i; } v; v.f = f;
  unsigned int r = v.i + 0x7fffu + ((v.i >> 16) & 1u);
  return (u16)(r >> 16);
}
__device__ __forceinline__ void gld16(const void* g, void* l) {
  __builtin_amdgcn_global_load_lds((const __attribute__((address_space(1))) void*)g,
                                   (__attribute__((address_space(3))) void*)l, 16, 0, 0);
}

// ---------------- router: logits, softmax, top-2, x->bf16, per-block partials ----------------
__global__ __launch_bounds__(256) void k_router(
    const float* __restrict__ x, const float* __restrict__ gw,
    float* __restrict__ part_imp, int* __restrict__ part_cnt,
    int* __restrict__ tok_e, float* __restrict__ tok_w,
    u16* __restrict__ xb)
{
  __shared__ float s_imp[8];
  __shared__ int s_cnt[8];
  if (threadIdx.x < 8) { s_imp[threadIdx.x] = 0.f; s_cnt[threadIdx.x] = 0; }
  __syncthreads();

  const int t = blockIdx.x * 4 + (threadIdx.x >> 6);
  const int lane = threadIdx.x & 63;
  const float* xr = x + (size_t)t * H_;
  const f32x4* xp = (const f32x4*)(xr + lane * 16);
  f32x4 v0 = xp[0], v1 = xp[1], v2 = xp[2], v3 = xp[3];
  float xv[16];
#pragma unroll
  for (int b = 0; b < 4; ++b) { xv[b] = v0[b]; xv[4+b] = v1[b]; xv[8+b] = v2[b]; xv[12+b] = v3[b]; }
  u16x8 o0, o1;
#pragma unroll
  for (int j = 0; j < 8; ++j) { o0[j] = f2bf(xv[j]); o1[j] = f2bf(xv[8 + j]); }
  *(u16x8*)(xb + (size_t)t * H_ + lane * 16) = o0;
  *(u16x8*)(xb + (size_t)t * H_ + lane * 16 + 8) = o1;

  float lg[8];
#pragma unroll
  for (int e = 0; e < 8; ++e) {
    const f32x4* gp = (const f32x4*)(gw + e * H_ + lane * 16);
    float s = 0.f;
#pragma unroll
    for (int a = 0; a < 4; ++a) {
      f32x4 g4 = gp[a];
#pragma unroll
      for (int b = 0; b < 4; ++b) s += xv[a * 4 + b] * g4[b];
    }
    lg[e] = s;
  }
#pragma unroll
  for (int e = 0; e < 8; ++e)
#pragma unroll
    for (int off = 32; off; off >>= 1) lg[e] += __shfl_xor(lg[e], off);

  float m = lg[0];
#pragma unroll
  for (int e = 1; e < 8; ++e) m = fmaxf(m, lg[e]);
  float p[8], sum = 0.f;
#pragma unroll
  for (int e = 0; e < 8; ++e) { p[e] = __expf(lg[e] - m); sum += p[e]; }
  float inv = 1.f / sum;
#pragma unroll
  for (int e = 0; e < 8; ++e) p[e] *= inv;
  int e0 = 0;
#pragma unroll
  for (int e = 1; e < 8; ++e) if (p[e] > p[e0]) e0 = e;
  int e1 = (e0 == 0) ? 1 : 0;
#pragma unroll
  for (int e = 0; e < 8; ++e) if (e != e0 && p[e] > p[e1]) e1 = e;
  float d = 1.f / (p[e0] + p[e1]);
  if (lane == 0) {
#pragma unroll
    for (int e = 0; e < 8; ++e) atomicAdd(&s_imp[e], p[e]);   // LDS atomics only
    atomicAdd(&s_cnt[e0], 1);
    atomicAdd(&s_cnt[e1], 1);
    tok_e[2 * t] = e0; tok_e[2 * t + 1] = e1;
    tok_w[2 * t] = p[e0] * d; tok_w[2 * t + 1] = p[e1] * d;
  }
  __syncthreads();
  if (threadIdx.x < 8) {
    part_imp[blockIdx.x * 8 + threadIdx.x] = s_imp[threadIdx.x];
    part_cnt[blockIdx.x * 8 + threadIdx.x] = s_cnt[threadIdx.x];
  }
}

// ---------------- reduce partials + offsets + aux loss ----------------
__global__ __launch_bounds__(512) void k_reduce_scan(
    const float* __restrict__ part_imp, const int* __restrict__ part_cnt,
    int* __restrict__ counts, int* __restrict__ offsets, float* __restrict__ out)
{
  const int w = threadIdx.x >> 6, lane = threadIdx.x & 63;
  float si = 0.f; int sc = 0;
  for (int b = lane; b < NBR_; b += 64) { si += part_imp[b * 8 + w]; sc += part_cnt[b * 8 + w]; }
#pragma unroll
  for (int off = 32; off; off >>= 1) { si += __shfl_xor(si, off); sc += __shfl_xor(sc, off); }
  __shared__ float fimp[8];
  __shared__ int fcnt[8];
  if (lane == 0) { fimp[w] = si; fcnt[w] = sc; }
  __syncthreads();
  if (threadIdx.x == 0) {
    int off = 0; float aux = 0.f;
#pragma unroll
    for (int e = 0; e < 8; ++e) {
      counts[e] = fcnt[e]; offsets[e] = off; off += fcnt[e];
      aux += fimp[e] * (float)fcnt[e];
    }
    out[(size_t)T_ * H_] = 8.f * aux / ((float)T_ * (float)(2 * T_));
  }
}

// ---------------- scatter tokens into per-expert segments (block-aggregated) ----------------
__global__ __launch_bounds__(256) void k_scatter(
    const int* __restrict__ tok_e, const float* __restrict__ tok_w,
    const int* __restrict__ offsets, int* __restrict__ cursors,
    int* __restrict__ rows, float* __restrict__ wslot, int* __restrict__ t2s)
{
  __shared__ int lcnt[8], lbase[8];
  if (threadIdx.x < 8) lcnt[threadIdx.x] = 0;
  __syncthreads();
  const int t = blockIdx.x * 256 + threadIdx.x;
  const int e0 = tok_e[2 * t], e1 = tok_e[2 * t + 1];
  const int p0 = atomicAdd(&lcnt[e0], 1);
  const int p1 = atomicAdd(&lcnt[e1], 1);
  __syncthreads();
  if (threadIdx.x < 8) lbase[threadIdx.x] = atomicAdd(&cursors[threadIdx.x], lcnt[threadIdx.x]);
  __syncthreads();
  const int s0 = offsets[e0] + lbase[e0] + p0;
  const int s1 = offsets[e1] + lbase[e1] + p1;
  rows[s0] = t; wslot[s0] = tok_w[2 * t];     t2s[2 * t] = s0;
  rows[s1] = t; wslot[s1] = tok_w[2 * t + 1]; t2s[2 * t + 1] = s1;
}

// ---------------- transpose+convert: src[z][R][C] f32 -> dst[z][C][R] bf16 ----------------
__global__ __launch_bounds__(256) void k_transpose(
    const float* __restrict__ src, u16* __restrict__ dst, int R, int C)
{
  __shared__ float tile[32][33];
  const int z = blockIdx.z;
  const int c0 = blockIdx.x * 32, r0 = blockIdx.y * 32;
  const float* s = src + (size_t)z * R * C;
  u16* d = dst + (size_t)z * R * C;
  const int tx = threadIdx.x & 31, ty = threadIdx.x >> 5;
#pragma unroll
  for (int i = 0; i < 4; ++i)
    tile[ty + i * 8][tx] = s[(size_t)(r0 + ty + i * 8) * C + c0 + tx];
  __syncthreads();
#pragma unroll
  for (int i = 0; i < 4; ++i)
    d[(size_t)(c0 + ty + i * 8) * R + r0 + tx] = f2bf(tile[tx][ty + i * 8]);
}

// ---------------- GEMM1: 256x128(act) tile, 2-phase dbuf, 8 waves ----------------
// C = [A(256 gathered rows) x K=1024] * [B(128 gate + 128 up rows) x K]^T
__global__ __launch_bounds__(512, 2) void k_gemm1(
    const u16* __restrict__ xb, const u16* __restrict__ wgu_t,
    const int* __restrict__ counts, const int* __restrict__ offsets,
    const int* __restrict__ rows, const float* __restrict__ wslot,
    u16* __restrict__ act)
{
  extern __shared__ char sh[];
  // T1: 5632 blocks, 704/XCD = exactly one expert per XCD; x fastest within
  const int bid = blockIdx.x;
  const int l = (bid & 7) * 704 + (bid >> 3);
  const int e = l / 704;
  const int rm = l - e * 704;
  const int y = rm >> 5, x = rm & 31;
  const int cnt = counts[e];
  const int m0 = x * 256;
  if (m0 >= cnt) return;
  const int seg = offsets[e];
  const int segLast = seg + cnt - 1;
  const int n0 = y * 128;

  const int tid = threadIdx.x;
  const int wid = tid >> 6, lane = tid & 63;
  const int srow = tid >> 3;         // 0..63
  const int scol = (tid & 7) * 8;    // elem offset within 64-wide K window

  const u16* wge = wgu_t + (size_t)e * GU_ * H_;

  int tA[4];
#pragma unroll
  for (int i = 0; i < 4; ++i) {
    int slot = seg + m0 + i * 64 + srow;
    tA[i] = rows[slot > segLast ? segLast : slot];
  }
  const u16* bSrc[4];
#pragma unroll
  for (int i = 0; i < 4; ++i) {
    int r = i * 64 + srow;                       // 0..255: 0-127 gate, 128-255 up
    int gr = (r < 128) ? (n0 + r) : (I_ + n0 + (r - 128));
    bSrc[i] = wge + (size_t)gr * H_;
  }

  const int wm = (wid >> 2) * 128;   // 2 wave-rows
  const int wn = (wid & 3) * 32;     // 4 wave-cols

  f32x4 accg[8][2], accu[8][2];
#pragma unroll
  for (int i = 0; i < 8; ++i)
#pragma unroll
    for (int j = 0; j < 2; ++j) { accg[i][j] = (f32x4){0.f,0.f,0.f,0.f}; accu[i][j] = (f32x4){0.f,0.f,0.f,0.f}; }

  // buf layout: [A 32KB][B 32KB] per buffer, buffers at 0 / 65536
#define STAGE1(b, kt)                                                             \
  {                                                                               \
    const int k0 = (kt) * 64;                                                     \
    char* base = sh + (b) * 65536 + wid * 1024;                                   \
    _Pragma("unroll")                                                             \
    for (int i = 0; i < 4; ++i)                                                   \
      gld16(xb + (size_t)tA[i] * H_ + k0 + scol, base + i * 8192);                \
    _Pragma("unroll")                                                             \
    for (int i = 0; i < 4; ++i)                                                   \
      gld16(bSrc[i] + k0 + scol, base + 32768 + i * 8192);                        \
  }

  STAGE1(0, 0);
  __syncthreads();
  int cur = 0;
  for (int kt = 0; kt < 16; ++kt) {
    if (kt < 15) STAGE1(cur ^ 1, kt + 1);      // prefetch next K-tile
    const u16* At = (const u16*)(sh + cur * 65536);
    const u16* Bt = At + 16384;
#pragma unroll
    for (int ks = 0; ks < 2; ++ks) {
      const int kk = ks * 32 + (lane >> 4) * 8;
      bf16x8 a[8], bg[2], bu[2];
#pragma unroll
      for (int mf = 0; mf < 8; ++mf)
        a[mf] = *(const bf16x8*)(At + (wm + mf * 16 + (lane & 15)) * 64 + kk);
#pragma unroll
      for (int nf = 0; nf < 2; ++nf) {
        bg[nf] = *(const bf16x8*)(Bt + (wn + nf * 16 + (lane & 15)) * 64 + kk);
        bu[nf] = *(const bf16x8*)(Bt + (128 + wn + nf * 16 + (lane & 15)) * 64 + kk);
      }
#pragma unroll
      for (int mf = 0; mf < 8; ++mf)
#pragma unroll
        for (int nf = 0; nf < 2; ++nf) {
          accg[mf][nf] = __builtin_amdgcn_mfma_f32_16x16x32_bf16(a[mf], bg[nf], accg[mf][nf], 0, 0, 0);
          accu[mf][nf] = __builtin_amdgcn_mfma_f32_16x16x32_bf16(a[mf], bu[nf], accu[mf][nf], 0, 0, 0);
        }
    }
    __syncthreads();   // drains prefetch vmcnt + protects buffers
    cur ^= 1;
  }

#pragma unroll
  for (int mf = 0; mf < 8; ++mf)
#pragma unroll
    for (int reg = 0; reg < 4; ++reg) {
      const int r = wm + mf * 16 + (lane >> 4) * 4 + reg;
      if (m0 + r >= cnt) continue;
      const int slot = seg + m0 + r;
      const float w = wslot[slot];
#pragma unroll
      for (int nf = 0; nf < 2; ++nf) {
        float g = accg[mf][nf][reg];
        float u = accu[mf][nf][reg];
        float sv = (g / (1.f + __expf(-g))) * u * w;
        act[(size_t)slot * I_ + n0 + wn + nf * 16 + (lane & 15)] = f2bf(sv);
      }
    }
#undef STAGE1
}

// ---------------- GEMM2: 256x128 tile, 2-phase dbuf, 8 waves ----------------
__global__ __launch_bounds__(512, 2) void k_gemm2(
    const u16* __restrict__ act, const u16* __restrict__ wd_t,
    const int* __restrict__ counts, const int* __restrict__ offsets,
    u16* __restrict__ y)
{
  extern __shared__ char sh[];
  // T1: 2048 blocks, 256/XCD = one expert per XCD
  const int bid = blockIdx.x;
  const int l = (bid & 7) * 256 + (bid >> 3);
  const int e = l >> 8;
  const int yb = (l >> 5) & 7, x = l & 31;
  const int cnt = counts[e];
  const int m0 = x * 256;
  if (m0 >= cnt) return;
  const int seg = offsets[e];
  const int segLast = seg + cnt - 1;
  const int n0 = yb * 128;

  const int tid = threadIdx.x;
  const int wid = tid >> 6, lane = tid & 63;
  const int srow = tid >> 3, scol = (tid & 7) * 8;

  const u16* wde = wd_t + (size_t)e * H_ * I_;

  int aS[4];
#pragma unroll
  for (int i = 0; i < 4; ++i) {
    int slot = seg + m0 + i * 64 + srow;
    aS[i] = slot > segLast ? segLast : slot;
  }
  const u16* bSrc[2];
#pragma unroll
  for (int i = 0; i < 2; ++i)
    bSrc[i] = wde + (size_t)(n0 + i * 64 + srow) * I_;

  const int wm = (wid >> 2) * 128;
  const int wn = (wid & 3) * 32;

  f32x4 acc[8][2];
#pragma unroll
  for (int i = 0; i < 8; ++i)
#pragma unroll
    for (int j = 0; j < 2; ++j) acc[i][j] = (f32x4){0.f,0.f,0.f,0.f};

  // buf layout: [A 32KB][B 16KB] per buffer, stride 49152
#define STAGE2(b, kt)                                                             \
  {                                                                               \
    const int k0 = (kt) * 64;                                                     \
    char* base = sh + (b) * 49152 + wid * 1024;                                   \
    _Pragma("unroll")                                                             \
    for (int i = 0; i < 4; ++i)                                                   \
      gld16(act + (size_t)aS[i] * I_ + k0 + scol, base + i * 8192);               \
    _Pragma("unroll")                                                             \
    for (int i = 0; i < 2; ++i)                                                   \
      gld16(bSrc[i] + k0 + scol, base + 32768 + i * 8192);                        \
  }

  STAGE2(0, 0);
  __syncthreads();
  int cur = 0;
  for (int kt = 0; kt < 44; ++kt) {
    if (kt < 43) STAGE2(cur ^ 1, kt + 1);
    const u16* At = (const u16*)(sh + cur * 49152);
    const u16* Bt = At + 16384;
#pragma unroll
    for (int ks = 0; ks < 2; ++ks) {
      const int kk = ks * 32 + (lane >> 4) * 8;
      bf16x8 a[8], b[2];
#pragma unroll
      for (int mf = 0; mf < 8; ++mf)
        a[mf] = *(const bf16x8*)(At + (wm + mf * 16 + (lane & 15)) * 64 + kk);
#pragma unroll
      for (int nf = 0; nf < 2; ++nf)
        b[nf] = *(const bf16x8*)(Bt + (wn + nf * 16 + (lane & 15)) * 64 + kk);
#pragma unroll
      for (int mf = 0; mf < 8; ++mf)
#pragma unroll
        for (int nf = 0; nf < 2; ++nf)
          acc[mf][nf] = __builtin_amdgcn_mfma_f32_16x16x32_bf16(a[mf], b[nf], acc[mf][nf], 0, 0, 0);
    }
    __syncthreads();
    cur ^= 1;
  }

#pragma unroll
  for (int mf = 0; mf < 8; ++mf)
#pragma unroll
    for (int reg = 0; reg < 4; ++reg) {
      const int r = wm + mf * 16 + (lane >> 4) * 4 + reg;
      if (m0 + r >= cnt) continue;
      const int slot = seg + m0 + r;
#pragma unroll
      for (int nf = 0; nf < 2; ++nf)
        y[(size_t)slot * H_ + n0 + wn + nf * 16 + (lane & 15)] = f2bf(acc[mf][nf][reg]);
    }
#undef STAGE2
}

// ---------------- combine: out[t] = y[slot0] + y[slot1] ----------------
__global__ __launch_bounds__(256) void k_combine(
    const u16* __restrict__ y, const int* __restrict__ t2s, float* __restrict__ out)
{
  const size_t idx = ((size_t)blockIdx.x * 256 + threadIdx.x) * 8;
  const int t = (int)(idx >> 10);
  const int h = (int)(idx & 1023);
  const int s0 = t2s[2 * t], s1 = t2s[2 * t + 1];
  u16x8 a = *(const u16x8*)(y + (size_t)s0 * H_ + h);
  u16x8 b = *(const u16x8*)(y + (size_t)s1 * H_ + h);
  f32x4 o0, o1;
#pragma unroll
  for (int j = 0; j < 4; ++j) o0[j] = bf2f(a[j]) + bf2f(b[j]);
#pragma unroll
  for (int j = 0; j < 4; ++j) o1[j] = bf2f(a[4 + j]) + bf2f(b[4 + j]);
  *(f32x4*)(out + idx) = o0;
  *(f32x4*)(out + idx + 4) = o1;
}

extern "C" void kernel_launch(void* const* d_in, const int* in_sizes, int n_in,
                              void* d_out, int out_size, void* d_ws, size_t ws_size,
                              hipStream_t stream)
{
  const float* x   = (const float*)d_in[0];
  const float* gw  = (const float*)d_in[1];
  const float* wgu = (const float*)d_in[2];
  const float* wd  = (const float*)d_in[3];
  float* out = (float*)d_out;
  char* ws = (char*)d_ws;

  const size_t off_wgu_t = 0;
  const size_t off_wd_t  = off_wgu_t + (size_t)E_ * GU_ * H_ * 2;   // 92,274,688
  const size_t off_xb    = off_wd_t  + (size_t)E_ * H_ * I_ * 2;    // +46,137,344
  const size_t off_act   = off_xb    + (size_t)T_ * H_ * 2;         // +16,777,216
  const size_t off_ctrl  = off_act   + (size_t)2 * T_ * I_ * 2;     // +92,274,688
  const size_t need = off_ctrl + 128 + 5 * 65536;
  if (ws_size < need) return;

  u16* wgu_t = (u16*)(ws + off_wgu_t);
  u16* wd_t  = (u16*)(ws + off_wd_t);
  u16* xb    = (u16*)(ws + off_xb);
  u16* act   = (u16*)(ws + off_act);
  u16* y     = (u16*)(ws + off_wgu_t);   // alias: wgu_t dead after gemm1
  float* part_imp = (float*)(ws + off_act);   // alias: act dead until gemm1
  int*   part_cnt = (int*)(ws + off_act + (size_t)NBR_ * 8 * 4);
  char* ctrl = ws + off_ctrl;
  int*   counts  = (int*)(ctrl + 0);
  int*   cursors = (int*)(ctrl + 32);
  int*   offsets = (int*)(ctrl + 64);
  int*   tok_e   = (int*)(ctrl + 128);
  float* tok_w   = (float*)(ctrl + 128 + 1 * 65536);
  int*   rows    = (int*)(ctrl + 128 + 2 * 65536);
  float* wslot   = (float*)(ctrl + 128 + 3 * 65536);
  int*   t2s     = (int*)(ctrl + 128 + 4 * 65536);

  // allow >64KB dynamic LDS (no-op if unnecessary; not a stream op, capture-safe)
  static bool attr_done = false;
  if (!attr_done) {
    hipFuncSetAttribute((const void*)k_gemm1, hipFuncAttributeMaxDynamicSharedMemorySize, 131072);
    hipFuncSetAttribute((const void*)k_gemm2, hipFuncAttributeMaxDynamicSharedMemorySize, 98304);
    attr_done = true;
  }

  hipMemsetAsync(ctrl, 0, 96, stream);
  hipLaunchKernelGGL(k_transpose, dim3(GU_ / 32, H_ / 32, E_), dim3(256), 0, stream, wgu, wgu_t, H_, GU_);
  hipLaunchKernelGGL(k_transpose, dim3(H_ / 32, I_ / 32, E_), dim3(256), 0, stream, wd, wd_t, I_, H_);
  hipLaunchKernelGGL(k_router, dim3(NBR_), dim3(256), 0, stream, x, gw, part_imp, part_cnt, tok_e, tok_w, xb);
  hipLaunchKernelGGL(k_reduce_scan, dim3(1), dim3(512), 0, stream, part_imp, part_cnt, counts, offsets, out);
  hipLaunchKernelGGL(k_scatter, dim3(T_ / 256), dim3(256), 0, stream, tok_e, tok_w, offsets, cursors, rows, wslot, t2s);
  hipLaunchKernelGGL(k_gemm1, dim3(32 * (I_ / 128) * E_), dim3(512), 131072, stream, xb, wgu_t, counts, offsets, rows, wslot, act);
  hipLaunchKernelGGL(k_gemm2, dim3(32 * (H_ / 128) * E_), dim3(512), 98304, stream, act, wd_t, counts, offsets, y);
  hipLaunchKernelGGL(k_combine, dim3((T_ * H_) / (256 * 8)), dim3(256), 0, stream, y, t2s, out);
}

// Round 4
// 546.536 us; speedup vs baseline: 3.0430x; 1.1997x over previous
//
#include <hip/hip_runtime.h>

#define E_ 8
#define H_ 1024
#define I_ 2816
#define GU_ 5632
#define T_ 8192
#define NBR_ 2048  // router blocks = T_/4

typedef __attribute__((ext_vector_type(8))) __bf16 bf16x8;
typedef __attribute__((ext_vector_type(4))) float f32x4;
typedef __attribute__((ext_vector_type(8))) unsigned short u16x8;
typedef unsigned short u16;

__device__ __forceinline__ float bf2f(u16 u) {
  union { unsigned int i; float f; } v; v.i = ((unsigned int)u) << 16; return v.f;
}
__device__ __forceinline__ u16 f2bf(float f) {
  union { float f; unsigned int i; } v; v.f = f;
  unsigned int r = v.i + 0x7fffu + ((v.i >> 16) & 1u);
  return (u16)(r >> 16);
}
__device__ __forceinline__ void gld16(const void* g, void* l) {
  __builtin_amdgcn_global_load_lds((const __attribute__((address_space(1))) void*)g,
                                   (__attribute__((address_space(3))) void*)l, 16, 0, 0);
}

// ---------------- router ----------------
__global__ __launch_bounds__(256) void k_router(
    const float* __restrict__ x, const float* __restrict__ gw,
    float* __restrict__ part_imp, int* __restrict__ part_cnt,
    int* __restrict__ tok_e, float* __restrict__ tok_w,
    u16* __restrict__ xb)
{
  __shared__ float s_imp[8];
  __shared__ int s_cnt[8];
  if (threadIdx.x < 8) { s_imp[threadIdx.x] = 0.f; s_cnt[threadIdx.x] = 0; }
  __syncthreads();

  const int t = blockIdx.x * 4 + (threadIdx.x >> 6);
  const int lane = threadIdx.x & 63;
  const float* xr = x + (size_t)t * H_;
  const f32x4* xp = (const f32x4*)(xr + lane * 16);
  f32x4 v0 = xp[0], v1 = xp[1], v2 = xp[2], v3 = xp[3];
  float xv[16];
#pragma unroll
  for (int b = 0; b < 4; ++b) { xv[b] = v0[b]; xv[4+b] = v1[b]; xv[8+b] = v2[b]; xv[12+b] = v3[b]; }
  u16x8 o0, o1;
#pragma unroll
  for (int j = 0; j < 8; ++j) { o0[j] = f2bf(xv[j]); o1[j] = f2bf(xv[8 + j]); }
  *(u16x8*)(xb + (size_t)t * H_ + lane * 16) = o0;
  *(u16x8*)(xb + (size_t)t * H_ + lane * 16 + 8) = o1;

  float lg[8];
#pragma unroll
  for (int e = 0; e < 8; ++e) {
    const f32x4* gp = (const f32x4*)(gw + e * H_ + lane * 16);
    float s = 0.f;
#pragma unroll
    for (int a = 0; a < 4; ++a) {
      f32x4 g4 = gp[a];
#pragma unroll
      for (int b = 0; b < 4; ++b) s += xv[a * 4 + b] * g4[b];
    }
    lg[e] = s;
  }
#pragma unroll
  for (int e = 0; e < 8; ++e)
#pragma unroll
    for (int off = 32; off; off >>= 1) lg[e] += __shfl_xor(lg[e], off);

  float m = lg[0];
#pragma unroll
  for (int e = 1; e < 8; ++e) m = fmaxf(m, lg[e]);
  float p[8], sum = 0.f;
#pragma unroll
  for (int e = 0; e < 8; ++e) { p[e] = __expf(lg[e] - m); sum += p[e]; }
  float inv = 1.f / sum;
#pragma unroll
  for (int e = 0; e < 8; ++e) p[e] *= inv;
  int e0 = 0;
#pragma unroll
  for (int e = 1; e < 8; ++e) if (p[e] > p[e0]) e0 = e;
  int e1 = (e0 == 0) ? 1 : 0;
#pragma unroll
  for (int e = 0; e < 8; ++e) if (e != e0 && p[e] > p[e1]) e1 = e;
  float d = 1.f / (p[e0] + p[e1]);
  if (lane == 0) {
#pragma unroll
    for (int e = 0; e < 8; ++e) atomicAdd(&s_imp[e], p[e]);
    atomicAdd(&s_cnt[e0], 1);
    atomicAdd(&s_cnt[e1], 1);
    tok_e[2 * t] = e0; tok_e[2 * t + 1] = e1;
    tok_w[2 * t] = p[e0] * d; tok_w[2 * t + 1] = p[e1] * d;
  }
  __syncthreads();
  if (threadIdx.x < 8) {
    part_imp[blockIdx.x * 8 + threadIdx.x] = s_imp[threadIdx.x];
    part_cnt[blockIdx.x * 8 + threadIdx.x] = s_cnt[threadIdx.x];
  }
}

// ---------------- reduce partials + offsets + aux loss ----------------
__global__ __launch_bounds__(512) void k_reduce_scan(
    const float* __restrict__ part_imp, const int* __restrict__ part_cnt,
    int* __restrict__ counts, int* __restrict__ offsets, float* __restrict__ out)
{
  const int w = threadIdx.x >> 6, lane = threadIdx.x & 63;
  float si = 0.f; int sc = 0;
  for (int b = lane; b < NBR_; b += 64) { si += part_imp[b * 8 + w]; sc += part_cnt[b * 8 + w]; }
#pragma unroll
  for (int off = 32; off; off >>= 1) { si += __shfl_xor(si, off); sc += __shfl_xor(sc, off); }
  __shared__ float fimp[8];
  __shared__ int fcnt[8];
  if (lane == 0) { fimp[w] = si; fcnt[w] = sc; }
  __syncthreads();
  if (threadIdx.x == 0) {
    int off = 0; float aux = 0.f;
#pragma unroll
    for (int e = 0; e < 8; ++e) {
      counts[e] = fcnt[e]; offsets[e] = off; off += fcnt[e];
      aux += fimp[e] * (float)fcnt[e];
    }
    out[(size_t)T_ * H_] = 8.f * aux / ((float)T_ * (float)(2 * T_));
  }
}

// ---------------- scatter (block-aggregated) ----------------
__global__ __launch_bounds__(256) void k_scatter(
    const int* __restrict__ tok_e, const float* __restrict__ tok_w,
    const int* __restrict__ offsets, int* __restrict__ cursors,
    int* __restrict__ rows, float* __restrict__ wslot, int* __restrict__ t2s)
{
  __shared__ int lcnt[8], lbase[8];
  if (threadIdx.x < 8) lcnt[threadIdx.x] = 0;
  __syncthreads();
  const int t = blockIdx.x * 256 + threadIdx.x;
  const int e0 = tok_e[2 * t], e1 = tok_e[2 * t + 1];
  const int p0 = atomicAdd(&lcnt[e0], 1);
  const int p1 = atomicAdd(&lcnt[e1], 1);
  __syncthreads();
  if (threadIdx.x < 8) lbase[threadIdx.x] = atomicAdd(&cursors[threadIdx.x], lcnt[threadIdx.x]);
  __syncthreads();
  const int s0 = offsets[e0] + lbase[e0] + p0;
  const int s1 = offsets[e1] + lbase[e1] + p1;
  rows[s0] = t; wslot[s0] = tok_w[2 * t];     t2s[2 * t] = s0;
  rows[s1] = t; wslot[s1] = tok_w[2 * t + 1]; t2s[2 * t + 1] = s1;
}

// ---------------- transpose+convert ----------------
__global__ __launch_bounds__(256) void k_transpose(
    const float* __restrict__ src, u16* __restrict__ dst, int R, int C)
{
  __shared__ float tile[32][33];
  const int z = blockIdx.z;
  const int c0 = blockIdx.x * 32, r0 = blockIdx.y * 32;
  const float* s = src + (size_t)z * R * C;
  u16* d = dst + (size_t)z * R * C;
  const int tx = threadIdx.x & 31, ty = threadIdx.x >> 5;
#pragma unroll
  for (int i = 0; i < 4; ++i)
    tile[ty + i * 8][tx] = s[(size_t)(r0 + ty + i * 8) * C + c0 + tx];
  __syncthreads();
#pragma unroll
  for (int i = 0; i < 4; ++i)
    d[(size_t)(c0 + ty + i * 8) * R + r0 + tx] = f2bf(tile[tx][ty + i * 8]);
}

// ============ GEMM1: 256 rows x (128 gate + 128 up), BK=64, counted-vmcnt pipeline ============
__global__ __launch_bounds__(512, 2) void k_gemm1(
    const u16* __restrict__ xb, const u16* __restrict__ wgu_t,
    const int* __restrict__ counts, const int* __restrict__ offsets,
    const int* __restrict__ rows, const float* __restrict__ wslot,
    u16* __restrict__ act)
{
  extern __shared__ char sh[];
  const int bid = blockIdx.x;                 // 5632 blocks: 704/XCD = one expert/XCD
  const int l = (bid & 7) * 704 + (bid >> 3);
  const int e = l / 704;
  const int rm = l - e * 704;
  const int yb = rm >> 5, xx = rm & 31;
  const int cnt = counts[e];
  const int m0 = xx * 256;
  if (m0 >= cnt) return;
  const int seg = offsets[e];
  const int segLast = seg + cnt - 1;
  const int n0 = yb * 128;

  const int tid = threadIdx.x;
  const int wid = tid >> 6, lane = tid & 63;
  const int srow = tid >> 3;                        // 0..63
  const int scol = (((tid & 7) ^ (srow & 7)) * 8);  // T2: pre-swizzled global col (elems)

  const u16* wge = wgu_t + (size_t)e * GU_ * H_;

  const u16* aPtr[4];
#pragma unroll
  for (int i = 0; i < 4; ++i) {
    int slot = seg + m0 + i * 64 + srow;
    aPtr[i] = xb + (size_t)rows[slot > segLast ? segLast : slot] * H_ + scol;
  }
  const u16* bPtr[4];
#pragma unroll
  for (int i = 0; i < 4; ++i) {
    int r = i * 64 + srow;                          // 0..255: 0-127 gate, 128-255 up
    int gr = (r < 128) ? (n0 + r) : (I_ + n0 + (r - 128));
    bPtr[i] = wge + (size_t)gr * H_ + scol;
  }

  const int wm = (wid >> 2) * 128;   // wave rows: 2 x 128
  const int wn = (wid & 3) * 32;     // wave cols: 4 x 32 (within gate 128)

  f32x4 accg[8][2], accu[8][2];
#pragma unroll
  for (int i = 0; i < 8; ++i)
#pragma unroll
    for (int j = 0; j < 2; ++j) { accg[i][j] = (f32x4){0.f,0.f,0.f,0.f}; accu[i][j] = (f32x4){0.f,0.f,0.f,0.f}; }

  // buffer: [A 32KB][B 32KB], buffers at 0 / 65536. Linear LDS dest (rule #21).
#define STAGE_A1(b, kt) { const int k0 = (kt) * 64;                               \
    char* dst = sh + (b) * 65536 + tid * 16;                                      \
    _Pragma("unroll") for (int i = 0; i < 4; ++i) gld16(aPtr[i] + k0, dst + i * 8192); }
#define STAGE_B1(b, kt) { const int k0 = (kt) * 64;                               \
    char* dst = sh + (b) * 65536 + 32768 + tid * 16;                              \
    _Pragma("unroll") for (int i = 0; i < 4; ++i) gld16(bPtr[i] + k0, dst + i * 8192); }

  const int NT = H_ / 64;  // 16
  // Prologue: A0,B0 (tile0), A1 (tile1) -> wait oldest 8 (=tile0) -> 4 in flight
  STAGE_A1(0, 0); STAGE_B1(0, 0); STAGE_A1(1, 1);
  asm volatile("s_waitcnt vmcnt(4)" ::: "memory");
  __builtin_amdgcn_s_barrier();

  int cur = 0;
#pragma unroll 2
  for (int t = 0; t < NT; ++t) {
    STAGE_B1(cur ^ 1, (t + 1 < NT) ? t + 1 : NT - 1);      // B of tile t+1
    const u16* As = (const u16*)(sh + cur * 65536);
    const u16* Bs = As + 16384;
#pragma unroll
    for (int ks = 0; ks < 2; ++ks) {
      const int koff = (ks * 32 + (lane >> 4) * 8) ^ ((lane & 7) * 8);  // T2 read swizzle
      bf16x8 a[8], bg[2], bu[2];
#pragma unroll
      for (int mf = 0; mf < 8; ++mf)
        a[mf] = *(const bf16x8*)(As + (wm + mf * 16 + (lane & 15)) * 64 + koff);
#pragma unroll
      for (int nf = 0; nf < 2; ++nf) {
        bg[nf] = *(const bf16x8*)(Bs + (wn + nf * 16 + (lane & 15)) * 64 + koff);
        bu[nf] = *(const bf16x8*)(Bs + (128 + wn + nf * 16 + (lane & 15)) * 64 + koff);
      }
      __builtin_amdgcn_s_setprio(1);
#pragma unroll
      for (int mf = 0; mf < 8; ++mf)
#pragma unroll
        for (int nf = 0; nf < 2; ++nf) {
          accg[mf][nf] = __builtin_amdgcn_mfma_f32_16x16x32_bf16(a[mf], bg[nf], accg[mf][nf], 0, 0, 0);
          accu[mf][nf] = __builtin_amdgcn_mfma_f32_16x16x32_bf16(a[mf], bu[nf], accu[mf][nf], 0, 0, 0);
        }
      __builtin_amdgcn_s_setprio(0);
    }
    asm volatile("" ::: "memory");
    __builtin_amdgcn_s_barrier();                          // all reads of buf[cur] done
    STAGE_A1(cur, (t + 2 < NT) ? t + 2 : NT - 1);          // A of tile t+2 into freed buf
    asm volatile("s_waitcnt vmcnt(4)" ::: "memory");       // tile t+1 fully landed
    __builtin_amdgcn_s_barrier();
    cur ^= 1;
  }
  asm volatile("s_waitcnt vmcnt(0)" ::: "memory");  // drain clamped tail loads (LDS safety)
#undef STAGE_A1
#undef STAGE_B1

#pragma unroll
  for (int mf = 0; mf < 8; ++mf)
#pragma unroll
    for (int reg = 0; reg < 4; ++reg) {
      const int r = wm + mf * 16 + (lane >> 4) * 4 + reg;
      if (m0 + r >= cnt) continue;
      const int slot = seg + m0 + r;
      const float w = wslot[slot];
#pragma unroll
      for (int nf = 0; nf < 2; ++nf) {
        float g = accg[mf][nf][reg];
        float u = accu[mf][nf][reg];
        float sv = (g / (1.f + __expf(-g))) * u * w;
        act[(size_t)slot * I_ + n0 + wn + nf * 16 + (lane & 15)] = f2bf(sv);
      }
    }
}

// ============ GEMM2: 256 x 256, BK=64, counted-vmcnt pipeline ============
__global__ __launch_bounds__(512, 2) void k_gemm2(
    const u16* __restrict__ act, const u16* __restrict__ wd_t,
    const int* __restrict__ counts, const int* __restrict__ offsets,
    u16* __restrict__ y)
{
  extern __shared__ char sh[];
  const int bid = blockIdx.x;                 // 1024 blocks: 128/XCD = one expert/XCD
  const int l = (bid & 7) * 128 + (bid >> 3);
  const int e = l >> 7;
  const int rm = l & 127;
  const int yb = rm >> 5, xx = rm & 31;
  const int cnt = counts[e];
  const int m0 = xx * 256;
  if (m0 >= cnt) return;
  const int seg = offsets[e];
  const int segLast = seg + cnt - 1;
  const int n0 = yb * 256;

  const int tid = threadIdx.x;
  const int wid = tid >> 6, lane = tid & 63;
  const int srow = tid >> 3;
  const int scol = (((tid & 7) ^ (srow & 7)) * 8);

  const u16* wde = wd_t + (size_t)e * H_ * I_;

  const u16* aPtr[4];
#pragma unroll
  for (int i = 0; i < 4; ++i) {
    int slot = seg + m0 + i * 64 + srow;
    aPtr[i] = act + (size_t)(slot > segLast ? segLast : slot) * I_ + scol;
  }
  const u16* bPtr[4];
#pragma unroll
  for (int i = 0; i < 4; ++i)
    bPtr[i] = wde + (size_t)(n0 + i * 64 + srow) * I_ + scol;

  const int wm = (wid >> 2) * 128;
  const int wn = (wid & 3) * 64;

  f32x4 acc[8][4];
#pragma unroll
  for (int i = 0; i < 8; ++i)
#pragma unroll
    for (int j = 0; j < 4; ++j) acc[i][j] = (f32x4){0.f,0.f,0.f,0.f};

#define STAGE_A2(b, kt) { const int k0 = (kt) * 64;                               \
    char* dst = sh + (b) * 65536 + tid * 16;                                      \
    _Pragma("unroll") for (int i = 0; i < 4; ++i) gld16(aPtr[i] + k0, dst + i * 8192); }
#define STAGE_B2(b, kt) { const int k0 = (kt) * 64;                               \
    char* dst = sh + (b) * 65536 + 32768 + tid * 16;                              \
    _Pragma("unroll") for (int i = 0; i < 4; ++i) gld16(bPtr[i] + k0, dst + i * 8192); }

  const int NT = I_ / 64;  // 44
  STAGE_A2(0, 0); STAGE_B2(0, 0); STAGE_A2(1, 1);
  asm volatile("s_waitcnt vmcnt(4)" ::: "memory");
  __builtin_amdgcn_s_barrier();

  int cur = 0;
#pragma unroll 2
  for (int t = 0; t < NT; ++t) {
    STAGE_B2(cur ^ 1, (t + 1 < NT) ? t + 1 : NT - 1);
    const u16* As = (const u16*)(sh + cur * 65536);
    const u16* Bs = As + 16384;
#pragma unroll
    for (int ks = 0; ks < 2; ++ks) {
      const int koff = (ks * 32 + (lane >> 4) * 8) ^ ((lane & 7) * 8);
      bf16x8 a[8], b[4];
#pragma unroll
      for (int mf = 0; mf < 8; ++mf)
        a[mf] = *(const bf16x8*)(As + (wm + mf * 16 + (lane & 15)) * 64 + koff);
#pragma unroll
      for (int nf = 0; nf < 4; ++nf)
        b[nf] = *(const bf16x8*)(Bs + (wn + nf * 16 + (lane & 15)) * 64 + koff);
      __builtin_amdgcn_s_setprio(1);
#pragma unroll
      for (int mf = 0; mf < 8; ++mf)
#pragma unroll
        for (int nf = 0; nf < 4; ++nf)
          acc[mf][nf] = __builtin_amdgcn_mfma_f32_16x16x32_bf16(a[mf], b[nf], acc[mf][nf], 0, 0, 0);
      __builtin_amdgcn_s_setprio(0);
    }
    asm volatile("" ::: "memory");
    __builtin_amdgcn_s_barrier();
    STAGE_A2(cur, (t + 2 < NT) ? t + 2 : NT - 1);
    asm volatile("s_waitcnt vmcnt(4)" ::: "memory");
    __builtin_amdgcn_s_barrier();
    cur ^= 1;
  }
  asm volatile("s_waitcnt vmcnt(0)" ::: "memory");
#undef STAGE_A2
#undef STAGE_B2

#pragma unroll
  for (int mf = 0; mf < 8; ++mf)
#pragma unroll
    for (int reg = 0; reg < 4; ++reg) {
      const int r = wm + mf * 16 + (lane >> 4) * 4 + reg;
      if (m0 + r >= cnt) continue;
      const int slot = seg + m0 + r;
#pragma unroll
      for (int nf = 0; nf < 4; ++nf)
        y[(size_t)slot * H_ + n0 + wn + nf * 16 + (lane & 15)] = f2bf(acc[mf][nf][reg]);
    }
}

// ---------------- combine ----------------
__global__ __launch_bounds__(256) void k_combine(
    const u16* __restrict__ y, const int* __restrict__ t2s, float* __restrict__ out)
{
  const size_t idx = ((size_t)blockIdx.x * 256 + threadIdx.x) * 8;
  const int t = (int)(idx >> 10);
  const int h = (int)(idx & 1023);
  const int s0 = t2s[2 * t], s1 = t2s[2 * t + 1];
  u16x8 a = *(const u16x8*)(y + (size_t)s0 * H_ + h);
  u16x8 b = *(const u16x8*)(y + (size_t)s1 * H_ + h);
  f32x4 o0, o1;
#pragma unroll
  for (int j = 0; j < 4; ++j) o0[j] = bf2f(a[j]) + bf2f(b[j]);
#pragma unroll
  for (int j = 0; j < 4; ++j) o1[j] = bf2f(a[4 + j]) + bf2f(b[4 + j]);
  *(f32x4*)(out + idx) = o0;
  *(f32x4*)(out + idx + 4) = o1;
}

extern "C" void kernel_launch(void* const* d_in, const int* in_sizes, int n_in,
                              void* d_out, int out_size, void* d_ws, size_t ws_size,
                              hipStream_t stream)
{
  const float* x   = (const float*)d_in[0];
  const float* gw  = (const float*)d_in[1];
  const float* wgu = (const float*)d_in[2];
  const float* wd  = (const float*)d_in[3];
  float* out = (float*)d_out;
  char* ws = (char*)d_ws;

  const size_t off_wgu_t = 0;
  const size_t off_wd_t  = off_wgu_t + (size_t)E_ * GU_ * H_ * 2;
  const size_t off_xb    = off_wd_t  + (size_t)E_ * H_ * I_ * 2;
  const size_t off_act   = off_xb    + (size_t)T_ * H_ * 2;
  const size_t off_ctrl  = off_act   + (size_t)2 * T_ * I_ * 2;
  const size_t need = off_ctrl + 128 + 5 * 65536;
  if (ws_size < need) return;

  u16* wgu_t = (u16*)(ws + off_wgu_t);
  u16* wd_t  = (u16*)(ws + off_wd_t);
  u16* xb    = (u16*)(ws + off_xb);
  u16* act   = (u16*)(ws + off_act);
  u16* y     = (u16*)(ws + off_wgu_t);        // alias: wgu_t dead after gemm1
  float* part_imp = (float*)(ws + off_act);   // alias: act dead until gemm1
  int*   part_cnt = (int*)(ws + off_act + (size_t)NBR_ * 8 * 4);
  char* ctrl = ws + off_ctrl;
  int*   counts  = (int*)(ctrl + 0);
  int*   cursors = (int*)(ctrl + 32);
  int*   offsets = (int*)(ctrl + 64);
  int*   tok_e   = (int*)(ctrl + 128);
  float* tok_w   = (float*)(ctrl + 128 + 1 * 65536);
  int*   rows    = (int*)(ctrl + 128 + 2 * 65536);
  float* wslot   = (float*)(ctrl + 128 + 3 * 65536);
  int*   t2s     = (int*)(ctrl + 128 + 4 * 65536);

  static bool attr_done = false;
  if (!attr_done) {
    hipFuncSetAttribute((const void*)k_gemm1, hipFuncAttributeMaxDynamicSharedMemorySize, 131072);
    hipFuncSetAttribute((const void*)k_gemm2, hipFuncAttributeMaxDynamicSharedMemorySize, 131072);
    attr_done = true;
  }

  hipMemsetAsync(ctrl, 0, 96, stream);
  hipLaunchKernelGGL(k_transpose, dim3(GU_ / 32, H_ / 32, E_), dim3(256), 0, stream, wgu, wgu_t, H_, GU_);
  hipLaunchKernelGGL(k_transpose, dim3(H_ / 32, I_ / 32, E_), dim3(256), 0, stream, wd, wd_t, I_, H_);
  hipLaunchKernelGGL(k_router, dim3(NBR_), dim3(256), 0, stream, x, gw, part_imp, part_cnt, tok_e, tok_w, xb);
  hipLaunchKernelGGL(k_reduce_scan, dim3(1), dim3(512), 0, stream, part_imp, part_cnt, counts, offsets, out);
  hipLaunchKernelGGL(k_scatter, dim3(T_ / 256), dim3(256), 0, stream, tok_e, tok_w, offsets, cursors, rows, wslot, t2s);
  hipLaunchKernelGGL(k_gemm1, dim3(32 * (I_ / 128) * E_), dim3(512), 131072, stream, xb, wgu_t, counts, offsets, rows, wslot, act);
  hipLaunchKernelGGL(k_gemm2, dim3(32 * (H_ / 256) * E_), dim3(512), 131072, stream, act, wd_t, counts, offsets, y);
  hipLaunchKernelGGL(k_combine, dim3((T_ * H_) / (256 * 8)), dim3(256), 0, stream, y, t2s, out);
}